// Round 1
// baseline (208.131 us; speedup 1.0000x reference)
//
#include <hip/hip_runtime.h>

#define BN 4096
#define DIM 256
#define TM 64
#define TN 64
#define BK 32
#define JSPLIT 8
#define MARGIN_F 0.3f
#define NEG_FILL_F 1e9f
#define PAD 4  // LDS row pad (keeps 16B alignment, breaks pow2 bank stride)

// ---------------- init: hp=0, hn=1e9, hist=0 ----------------
__global__ void tl_init(unsigned* __restrict__ hp, unsigned* __restrict__ hn,
                        int* __restrict__ hist) {
    int i = blockIdx.x * blockDim.x + threadIdx.x;
    if (i < BN) {
        hp[i] = 0u;                       // distances >= 0, so 0 is the identity for max
        hn[i] = __float_as_uint(NEG_FILL_F);
    }
    if (i < 512) hist[i] = 0;
}

// ---------------- norms: one wave per row ----------------
__global__ __launch_bounds__(256) void tl_norms(const float* __restrict__ E,
                                                float* __restrict__ norms) {
    int row  = blockIdx.x * 4 + (threadIdx.x >> 6);   // 4 waves per block
    int lane = threadIdx.x & 63;
    const float4* rp = reinterpret_cast<const float4*>(E + (size_t)row * DIM);
    float4 v = rp[lane];                               // 256 floats = exactly 64 float4
    float s = v.x * v.x + v.y * v.y + v.z * v.z + v.w * v.w;
    #pragma unroll
    for (int m = 32; m; m >>= 1) s += __shfl_xor(s, m, 64);
    if (lane == 0) norms[row] = s;
}

// ---------------- label histogram ----------------
__global__ void tl_hist(const int* __restrict__ labels, int* __restrict__ hist) {
    int i = blockIdx.x * blockDim.x + threadIdx.x;
    if (i < BN) atomicAdd(&hist[labels[i]], 1);
}

// ---------------- main fused tile kernel ----------------
__global__ __launch_bounds__(256) void tl_tile(const float* __restrict__ E,
                                               const int* __restrict__ labels,
                                               const float* __restrict__ norms,
                                               unsigned* __restrict__ hp,
                                               unsigned* __restrict__ hn) {
    __shared__ __align__(16) float As[BK][TM + PAD];
    __shared__ __align__(16) float Bs[BK][TN + PAD];

    const int tid = threadIdx.x;
    const int tx  = tid & 15;        // column group 0..15
    const int ty  = tid >> 4;        // row group    0..15
    const int iblk = blockIdx.x / JSPLIT;
    const int jblk = blockIdx.x % JSPLIT;
    const int i0    = iblk * TM;
    const int jbase = jblk * (BN / JSPLIT);

    int   myrow[4]; int mylab[4]; float mynorm[4];
    float hpv[4], hnv[4];
    #pragma unroll
    for (int r = 0; r < 4; ++r) {
        myrow[r]  = i0 + ty * 4 + r;
        mylab[r]  = labels[myrow[r]];
        mynorm[r] = norms[myrow[r]];
        hpv[r] = 0.0f;               // identity for max over nonneg distances
        hnv[r] = NEG_FILL_F;
    }

    const int ra = tid >> 3;         // 0..31 (staging row within half-tile)
    const int c4 = tid & 7;          // 0..7  (float4 column within 32-wide k chunk)

    for (int jt = 0; jt < (BN / JSPLIT) / TN; ++jt) {
        const int j0 = jbase + jt * TN;
        float acc[4][4];
        #pragma unroll
        for (int r = 0; r < 4; ++r)
            #pragma unroll
            for (int c = 0; c < 4; ++c) acc[r][c] = 0.0f;

        for (int kb = 0; kb < DIM; kb += BK) {
            __syncthreads();   // protect tiles from previous iteration's readers
            // stage A (rows i0..i0+63) and B (rows j0..j0+63), k-major transposed
            {
                float4 va0 = *reinterpret_cast<const float4*>(E + (size_t)(i0 + ra) * DIM + kb + c4 * 4);
                As[c4 * 4 + 0][ra] = va0.x; As[c4 * 4 + 1][ra] = va0.y;
                As[c4 * 4 + 2][ra] = va0.z; As[c4 * 4 + 3][ra] = va0.w;
                float4 va1 = *reinterpret_cast<const float4*>(E + (size_t)(i0 + 32 + ra) * DIM + kb + c4 * 4);
                As[c4 * 4 + 0][32 + ra] = va1.x; As[c4 * 4 + 1][32 + ra] = va1.y;
                As[c4 * 4 + 2][32 + ra] = va1.z; As[c4 * 4 + 3][32 + ra] = va1.w;
                float4 vb0 = *reinterpret_cast<const float4*>(E + (size_t)(j0 + ra) * DIM + kb + c4 * 4);
                Bs[c4 * 4 + 0][ra] = vb0.x; Bs[c4 * 4 + 1][ra] = vb0.y;
                Bs[c4 * 4 + 2][ra] = vb0.z; Bs[c4 * 4 + 3][ra] = vb0.w;
                float4 vb1 = *reinterpret_cast<const float4*>(E + (size_t)(j0 + 32 + ra) * DIM + kb + c4 * 4);
                Bs[c4 * 4 + 0][32 + ra] = vb1.x; Bs[c4 * 4 + 1][32 + ra] = vb1.y;
                Bs[c4 * 4 + 2][32 + ra] = vb1.z; Bs[c4 * 4 + 3][32 + ra] = vb1.w;
            }
            __syncthreads();

            #pragma unroll
            for (int k = 0; k < BK; ++k) {
                float4 av = *reinterpret_cast<const float4*>(&As[k][ty * 4]);
                float4 bv = *reinterpret_cast<const float4*>(&Bs[k][tx * 4]);
                float a[4] = {av.x, av.y, av.z, av.w};
                float b[4] = {bv.x, bv.y, bv.z, bv.w};
                #pragma unroll
                for (int r = 0; r < 4; ++r)
                    #pragma unroll
                    for (int c = 0; c < 4; ++c)
                        acc[r][c] = fmaf(a[r], b[c], acc[r][c]);
            }
        }

        // tile epilogue: dots -> distances -> masked running max/min
        #pragma unroll
        for (int c = 0; c < 4; ++c) {
            const int   j  = j0 + tx * 4 + c;
            const float nj = norms[j];
            const int   lj = labels[j];
            #pragma unroll
            for (int r = 0; r < 4; ++r) {
                float d2 = mynorm[r] + nj - 2.0f * acc[r][c];
                d2 = fmaxf(d2, 0.0f);
                float d = (d2 > 0.0f) ? sqrtf(d2) : 0.0f;  // ref's zero-distance guard
                if (mylab[r] == lj) {
                    if (j != myrow[r]) hpv[r] = fmaxf(hpv[r], d);
                } else {
                    hnv[r] = fminf(hnv[r], d);
                }
            }
        }
    }

    // reduce across the 16 tx-threads sharing each row (lanes differ only in tx bits)
    #pragma unroll
    for (int m = 1; m <= 8; m <<= 1) {
        #pragma unroll
        for (int r = 0; r < 4; ++r) {
            hpv[r] = fmaxf(hpv[r], __shfl_xor(hpv[r], m, 64));
            hnv[r] = fminf(hnv[r], __shfl_xor(hnv[r], m, 64));
        }
    }
    if (tx == 0) {
        #pragma unroll
        for (int r = 0; r < 4; ++r) {
            atomicMax(&hp[myrow[r]], __float_as_uint(hpv[r]));  // uint order == float order for x>=0
            atomicMin(&hn[myrow[r]], __float_as_uint(hnv[r]));
        }
    }
}

// ---------------- final scalar reduction ----------------
__global__ __launch_bounds__(1024) void tl_finish(const unsigned* __restrict__ hp,
                                                  const unsigned* __restrict__ hn,
                                                  const int* __restrict__ labels,
                                                  const int* __restrict__ hist,
                                                  float* __restrict__ out) {
    __shared__ float ssum[16];
    __shared__ float scnt[16];
    const int t = threadIdx.x;
    float sum = 0.0f, cnt = 0.0f;
    for (int i = t; i < BN; i += 1024) {
        const int h = hist[labels[i]];
        const bool valid = (h >= 2) && (h < BN);   // has_pos && has_neg
        const float per = fmaxf(__uint_as_float(hp[i]) - __uint_as_float(hn[i]) + MARGIN_F, 0.0f);
        if (valid) { sum += per; cnt += 1.0f; }
    }
    #pragma unroll
    for (int m = 32; m; m >>= 1) {
        sum += __shfl_xor(sum, m, 64);
        cnt += __shfl_xor(cnt, m, 64);
    }
    const int wid = t >> 6;
    if ((t & 63) == 0) { ssum[wid] = sum; scnt[wid] = cnt; }
    __syncthreads();
    if (t == 0) {
        float S = 0.0f, C = 0.0f;
        #pragma unroll
        for (int w = 0; w < 16; ++w) { S += ssum[w]; C += scnt[w]; }
        out[0] = (C > 0.0f) ? (S / fmaxf(C, 1.0f)) : 0.0f;
    }
}

extern "C" void kernel_launch(void* const* d_in, const int* in_sizes, int n_in,
                              void* d_out, int out_size, void* d_ws, size_t ws_size,
                              hipStream_t stream) {
    const float* E      = (const float*)d_in[0];
    const int*   labels = (const int*)d_in[1];

    float*    ws    = (float*)d_ws;
    float*    norms = ws;                        // [4096] f32
    unsigned* hp    = (unsigned*)(ws + 4096);    // [4096] u32 (bits of hardest-pos dist)
    unsigned* hn    = (unsigned*)(ws + 8192);    // [4096] u32 (bits of hardest-neg dist)
    int*      hist  = (int*)(ws + 12288);        // [512]  i32

    tl_init<<<16, 256, 0, stream>>>(hp, hn, hist);
    tl_norms<<<BN / 4, 256, 0, stream>>>(E, norms);
    tl_hist<<<16, 256, 0, stream>>>(labels, hist);
    tl_tile<<<(BN / TM) * JSPLIT, 256, 0, stream>>>(E, labels, norms, hp, hn);
    tl_finish<<<1, 1024, 0, stream>>>(hp, hn, labels, hist, (float*)d_out);
}

// Round 2
// 104.632 us; speedup vs baseline: 1.9892x; 1.9892x over previous
//
#include <hip/hip_runtime.h>

#define BN 4096
#define DIM 256
#define NBLK 32              // 4096/128 row-blocks
#define NPAIR 528            // NBLK*(NBLK+1)/2 upper-tri block pairs
#define MARGIN_F 0.3f
#define NEG_FILL_F 1e9f

typedef __attribute__((ext_vector_type(8))) __bf16 bf16x8;
typedef __attribute__((ext_vector_type(4))) float f32x4;

// fp32 -> bf16 round-to-nearest-even (inputs are normal floats, no NaN/Inf)
__device__ __forceinline__ ushort f2bf(float x) {
    unsigned u = __float_as_uint(x);
    return (ushort)((u + 0x7FFFu + ((u >> 16) & 1u)) >> 16);
}
__device__ __forceinline__ float bf2f(ushort b) {
    return __uint_as_float(((unsigned)b) << 16);
}

// async global->LDS, 16B per lane; LDS dest semantics: wave-uniform base + lane*16
__device__ __forceinline__ void gld_lds16(const void* g, void* l) {
    __builtin_amdgcn_global_load_lds(
        (const __attribute__((address_space(1))) unsigned int*)g,
        (__attribute__((address_space(3))) unsigned int*)l, 16, 0, 0);
}

// ---------------- prep: norms + hp/hn init + hist (block 0) + bf16 hi/lo split ----
// Ehi/Elo global layout is chunk-major: [kc = k/8][row][8 bf16], 16B per (kc,row).
__global__ __launch_bounds__(256) void tl_prep(const float* __restrict__ E,
                                               const int* __restrict__ labels,
                                               float* __restrict__ norms,
                                               unsigned* __restrict__ hp,
                                               unsigned* __restrict__ hn,
                                               int* __restrict__ hist,
                                               ushort* __restrict__ Ehi,
                                               ushort* __restrict__ Elo) {
    const int tid  = threadIdx.x;
    const int lane = tid & 63;
    const int row  = blockIdx.x * 4 + (tid >> 6);

    float4 v = reinterpret_cast<const float4*>(E + (size_t)row * DIM)[lane];
    float f[4] = {v.x, v.y, v.z, v.w};
    ushort hb[4], lb[4];
    float s = 0.0f;
    #pragma unroll
    for (int q = 0; q < 4; ++q) {
        s += f[q] * f[q];
        hb[q] = f2bf(f[q]);
        lb[q] = f2bf(f[q] - bf2f(hb[q]));
    }
    // lane holds k = lane*4..lane*4+3 -> chunk kc = lane/2, half = lane&1
    const int kc = lane >> 1, half = lane & 1;
    const size_t co = (((size_t)(kc * BN + row)) << 3) + (size_t)(half * 4);
    *reinterpret_cast<ushort4*>(Ehi + co) = make_ushort4(hb[0], hb[1], hb[2], hb[3]);
    *reinterpret_cast<ushort4*>(Elo + co) = make_ushort4(lb[0], lb[1], lb[2], lb[3]);

    #pragma unroll
    for (int m = 32; m; m >>= 1) s += __shfl_xor(s, m, 64);
    if (lane == 0) {
        norms[row] = s;
        hp[row] = 0u;                              // identity for max over d>=0
        hn[row] = __float_as_uint(NEG_FILL_F);     // ref's NEG_FILL
    }

    // label histogram, single block (no cross-block ordering needed)
    __shared__ int lh[512];
    if (blockIdx.x == 0) {
        for (int i = tid; i < 512; i += 256) lh[i] = 0;
        __syncthreads();
        for (int i = tid; i < BN; i += 256) atomicAdd(&lh[labels[i]], 1);
        __syncthreads();
        for (int i = tid; i < 512; i += 256) hist[i] = lh[i];
    }
}

// ---------------- main: split-bf16 MFMA Gram + fused distance/masked min-max ------
// One block per upper-tri 128x128 tile pair. 4 waves, each owns a 64x64 sub-tile.
__global__ __launch_bounds__(256) void tl_main(const ushort* __restrict__ Ehi,
                                               const ushort* __restrict__ Elo,
                                               const int* __restrict__ labels,
                                               const float* __restrict__ norms,
                                               unsigned* __restrict__ hp,
                                               unsigned* __restrict__ hn) {
    // LDS: [part: Ahi,Alo,Bhi,Blo][kc 0..3][m 0..127][8 bf16] = 32 KB, chunk-linear
    __shared__ __align__(16) ushort smem[16384];

    const int tid  = threadIdx.x;
    const int lane = tid & 63;
    const int wave = tid >> 6;
    const int wy = wave >> 1, wx = wave & 1;
    const int quad = lane >> 4, l15 = lane & 15;

    // decode blockIdx -> (ib <= jb) upper-tri pair
    int t = blockIdx.x, ib = 0, off = 0;
    while (off + (NBLK - ib) <= t) { off += NBLK - ib; ++ib; }
    const int jb = ib + (t - off);
    const int i0 = ib * 128, j0 = jb * 128;

    f32x4 acc[4][4];
    #pragma unroll
    for (int r = 0; r < 4; ++r)
        #pragma unroll
        for (int c = 0; c < 4; ++c)
            acc[r][c] = (f32x4){0.f, 0.f, 0.f, 0.f};

    for (int kb = 0; kb < DIM / 32; ++kb) {
        __syncthreads();   // previous iteration's frag reads complete
        #pragma unroll
        for (int s = 0; s < 8; ++s) {
            const int idx  = s * 256 + tid;          // 2048 16B chunks
            const int part = idx >> 9;               // 0:Ahi 1:Alo 2:Bhi 3:Blo
            const int kc   = (idx >> 7) & 3;
            const int m    = idx & 127;
            const ushort* src = (part & 1) ? Elo : Ehi;
            const int     base = (part < 2) ? i0 : j0;
            src += ((size_t)((kb * 4 + kc) * BN + base + m)) << 3;
            gld_lds16(src, &smem[idx << 3]);
        }
        __syncthreads();   // drains vmcnt -> LDS tiles ready

        bf16x8 ah[4], al[4];
        #pragma unroll
        for (int r = 0; r < 4; ++r) {
            const int mi = wy * 64 + r * 16 + l15;
            ah[r] = *reinterpret_cast<const bf16x8*>(&smem[(0 * 512 + quad * 128 + mi) * 8]);
            al[r] = *reinterpret_cast<const bf16x8*>(&smem[(1 * 512 + quad * 128 + mi) * 8]);
        }
        #pragma unroll
        for (int c = 0; c < 4; ++c) {
            const int ni = wx * 64 + c * 16 + l15;
            bf16x8 bh = *reinterpret_cast<const bf16x8*>(&smem[(2 * 512 + quad * 128 + ni) * 8]);
            bf16x8 bl = *reinterpret_cast<const bf16x8*>(&smem[(3 * 512 + quad * 128 + ni) * 8]);
            #pragma unroll
            for (int r = 0; r < 4; ++r) {
                acc[r][c] = __builtin_amdgcn_mfma_f32_16x16x32_bf16(ah[r], bh, acc[r][c], 0, 0, 0);
                acc[r][c] = __builtin_amdgcn_mfma_f32_16x16x32_bf16(ah[r], bl, acc[r][c], 0, 0, 0);
                acc[r][c] = __builtin_amdgcn_mfma_f32_16x16x32_bf16(al[r], bh, acc[r][c], 0, 0, 0);
            }
        }
    }

    // ---------- epilogue: dots -> distances -> masked row & col stats ----------
    // C layout (16x16x32): col = lane&15, row = quad*4 + reg   [measured m89/m91]
    const int rowBase = i0 + wy * 64;
    const int colBase = j0 + wx * 64;

    float nrow[4][4]; int lrow[4][4];
    #pragma unroll
    for (int r = 0; r < 4; ++r)
        #pragma unroll
        for (int e = 0; e < 4; ++e) {
            const int g = rowBase + r * 16 + quad * 4 + e;
            nrow[r][e] = norms[g];
            lrow[r][e] = labels[g];
        }
    float ncol[4]; int lcol[4];
    #pragma unroll
    for (int c = 0; c < 4; ++c) {
        const int g = colBase + c * 16 + l15;
        ncol[c] = norms[g];
        lcol[c] = labels[g];
    }

    float rmax[4][4], rmin[4][4], cmax[4], cmin[4];
    #pragma unroll
    for (int r = 0; r < 4; ++r)
        #pragma unroll
        for (int e = 0; e < 4; ++e) { rmax[r][e] = 0.0f; rmin[r][e] = NEG_FILL_F; }
    #pragma unroll
    for (int c = 0; c < 4; ++c) { cmax[c] = 0.0f; cmin[c] = NEG_FILL_F; }

    #pragma unroll
    for (int c = 0; c < 4; ++c) {
        const int gcol = colBase + c * 16 + l15;
        #pragma unroll
        for (int r = 0; r < 4; ++r) {
            #pragma unroll
            for (int e = 0; e < 4; ++e) {
                const int grow = rowBase + r * 16 + quad * 4 + e;
                float d2 = nrow[r][e] + ncol[c] - 2.0f * acc[r][c][e];
                d2 = fmaxf(d2, 0.0f);
                const float d = (d2 > 0.0f) ? sqrtf(d2) : 0.0f;
                if (lrow[r][e] == lcol[c]) {
                    if (grow != gcol) {
                        rmax[r][e] = fmaxf(rmax[r][e], d);
                        cmax[c]    = fmaxf(cmax[c], d);
                    }
                } else {
                    rmin[r][e] = fminf(rmin[r][e], d);
                    cmin[c]    = fminf(cmin[c], d);
                }
            }
        }
    }

    // row stats: reduce across the 16 lanes of each quad (lane bits 0..3)
    #pragma unroll
    for (int m = 1; m <= 8; m <<= 1) {
        #pragma unroll
        for (int r = 0; r < 4; ++r)
            #pragma unroll
            for (int e = 0; e < 4; ++e) {
                rmax[r][e] = fmaxf(rmax[r][e], __shfl_xor(rmax[r][e], m, 64));
                rmin[r][e] = fminf(rmin[r][e], __shfl_xor(rmin[r][e], m, 64));
            }
    }
    // col stats: reduce across quads (lane bits 4..5)
    #pragma unroll
    for (int m = 16; m <= 32; m <<= 1) {
        #pragma unroll
        for (int c = 0; c < 4; ++c) {
            cmax[c] = fmaxf(cmax[c], __shfl_xor(cmax[c], m, 64));
            cmin[c] = fminf(cmin[c], __shfl_xor(cmin[c], m, 64));
        }
    }

    // block-level combine in LDS (reuse staging memory), then global atomics
    unsigned* srhp = reinterpret_cast<unsigned*>(smem);  // [128]
    unsigned* srhn = srhp + 128;
    unsigned* schp = srhp + 256;
    unsigned* schn = srhp + 384;
    __syncthreads();   // all frag reads done; safe to overwrite smem
    if (tid < 128) {
        srhp[tid] = 0u;
        srhn[tid] = __float_as_uint(NEG_FILL_F);
        schp[tid] = 0u;
        schn[tid] = __float_as_uint(NEG_FILL_F);
    }
    __syncthreads();
    if (l15 == 0) {   // lanes 0,16,32,48 hold row results for their quad
        #pragma unroll
        for (int r = 0; r < 4; ++r)
            #pragma unroll
            for (int e = 0; e < 4; ++e) {
                const int lr = wy * 64 + r * 16 + quad * 4 + e;
                atomicMax(&srhp[lr], __float_as_uint(rmax[r][e]));
                atomicMin(&srhn[lr], __float_as_uint(rmin[r][e]));
            }
    }
    if (quad == 0) {  // lanes 0..15 hold col results
        #pragma unroll
        for (int c = 0; c < 4; ++c) {
            const int lc = wx * 64 + c * 16 + l15;
            atomicMax(&schp[lc], __float_as_uint(cmax[c]));
            atomicMin(&schn[lc], __float_as_uint(cmin[c]));
        }
    }
    __syncthreads();
    if (tid < 128) {
        atomicMax(&hp[i0 + tid], srhp[tid]);   // uint order == float order for x>=0
        atomicMin(&hn[i0 + tid], srhn[tid]);
        atomicMax(&hp[j0 + tid], schp[tid]);   // transposed contribution (d symmetric)
        atomicMin(&hn[j0 + tid], schn[tid]);
    }
}

// ---------------- final scalar reduction ----------------
__global__ __launch_bounds__(1024) void tl_finish(const unsigned* __restrict__ hp,
                                                  const unsigned* __restrict__ hn,
                                                  const int* __restrict__ labels,
                                                  const int* __restrict__ hist,
                                                  float* __restrict__ out) {
    __shared__ float ssum[16];
    __shared__ float scnt[16];
    const int t = threadIdx.x;
    float sum = 0.0f, cnt = 0.0f;
    for (int i = t; i < BN; i += 1024) {
        const int h = hist[labels[i]];
        const bool valid = (h >= 2) && (h < BN);   // has_pos && has_neg
        const float per = fmaxf(__uint_as_float(hp[i]) - __uint_as_float(hn[i]) + MARGIN_F, 0.0f);
        if (valid) { sum += per; cnt += 1.0f; }
    }
    #pragma unroll
    for (int m = 32; m; m >>= 1) {
        sum += __shfl_xor(sum, m, 64);
        cnt += __shfl_xor(cnt, m, 64);
    }
    const int wid = t >> 6;
    if ((t & 63) == 0) { ssum[wid] = sum; scnt[wid] = cnt; }
    __syncthreads();
    if (t == 0) {
        float S = 0.0f, C = 0.0f;
        #pragma unroll
        for (int w = 0; w < 16; ++w) { S += ssum[w]; C += scnt[w]; }
        out[0] = (C > 0.0f) ? (S / fmaxf(C, 1.0f)) : 0.0f;
    }
}

extern "C" void kernel_launch(void* const* d_in, const int* in_sizes, int n_in,
                              void* d_out, int out_size, void* d_ws, size_t ws_size,
                              hipStream_t stream) {
    const float* E      = (const float*)d_in[0];
    const int*   labels = (const int*)d_in[1];

    float*    ws    = (float*)d_ws;
    float*    norms = ws;                          // [4096] f32
    unsigned* hp    = (unsigned*)(ws + 4096);      // [4096] u32
    unsigned* hn    = (unsigned*)(ws + 8192);      // [4096] u32
    int*      hist  = (int*)(ws + 12288);          // [512]  i32
    ushort*   Ehi   = (ushort*)(ws + 16384);       // [32][4096][8] bf16 = 2 MB
    ushort*   Elo   = Ehi + (size_t)BN * DIM;      // 2 MB

    tl_prep<<<BN / 4, 256, 0, stream>>>(E, labels, norms, hp, hn, hist, Ehi, Elo);
    tl_main<<<NPAIR, 256, 0, stream>>>(Ehi, Elo, labels, norms, hp, hn);
    tl_finish<<<1, 1024, 0, stream>>>(hp, hn, labels, hist, (float*)d_out);
}

// Round 3
// 100.494 us; speedup vs baseline: 2.0711x; 1.0412x over previous
//
#include <hip/hip_runtime.h>

#define BN 4096
#define DIM 256
#define NBLK 32              // 4096/128 row-blocks
#define NPAIR 528            // NBLK*(NBLK+1)/2 upper-tri block pairs
#define MARGIN_F 0.3f
#define NEG_FILL_F 1e9f

typedef __attribute__((ext_vector_type(8))) __bf16 bf16x8;
typedef __attribute__((ext_vector_type(4))) float f32x4;

// fp32 -> bf16 round-to-nearest-even (inputs are normal floats, no NaN/Inf)
__device__ __forceinline__ ushort f2bf(float x) {
    unsigned u = __float_as_uint(x);
    return (ushort)((u + 0x7FFFu + ((u >> 16) & 1u)) >> 16);
}
__device__ __forceinline__ float bf2f(ushort b) {
    return __uint_as_float(((unsigned)b) << 16);
}

// async global->LDS, 16B per lane; LDS dest semantics: wave-uniform base + lane*16
__device__ __forceinline__ void gld_lds16(const void* g, void* l) {
    __builtin_amdgcn_global_load_lds(
        (const __attribute__((address_space(1))) unsigned int*)g,
        (__attribute__((address_space(3))) unsigned int*)l, 16, 0, 0);
}

// ---------------- prep: norms + hp/hn init + hist (block 0) + bf16 hi/lo split ----
// Ehi/Elo global layout is chunk-major: [kc = k/8][row][8 bf16], 16B per (kc,row).
__global__ __launch_bounds__(256) void tl_prep(const float* __restrict__ E,
                                               const int* __restrict__ labels,
                                               float* __restrict__ norms,
                                               unsigned* __restrict__ hp,
                                               unsigned* __restrict__ hn,
                                               int* __restrict__ hist,
                                               ushort* __restrict__ Ehi,
                                               ushort* __restrict__ Elo) {
    const int tid  = threadIdx.x;
    const int lane = tid & 63;
    const int row  = blockIdx.x * 4 + (tid >> 6);

    float4 v = reinterpret_cast<const float4*>(E + (size_t)row * DIM)[lane];
    float f[4] = {v.x, v.y, v.z, v.w};
    ushort hb[4], lb[4];
    float s = 0.0f;
    #pragma unroll
    for (int q = 0; q < 4; ++q) {
        s += f[q] * f[q];
        hb[q] = f2bf(f[q]);
        lb[q] = f2bf(f[q] - bf2f(hb[q]));
    }
    // lane holds k = lane*4..lane*4+3 -> chunk kc = lane/2, half = lane&1
    const int kc = lane >> 1, half = lane & 1;
    const size_t co = (((size_t)(kc * BN + row)) << 3) + (size_t)(half * 4);
    *reinterpret_cast<ushort4*>(Ehi + co) = make_ushort4(hb[0], hb[1], hb[2], hb[3]);
    *reinterpret_cast<ushort4*>(Elo + co) = make_ushort4(lb[0], lb[1], lb[2], lb[3]);

    #pragma unroll
    for (int m = 32; m; m >>= 1) s += __shfl_xor(s, m, 64);
    if (lane == 0) {
        norms[row] = s;
        hp[row] = 0u;                              // identity for max over d>=0
        hn[row] = __float_as_uint(NEG_FILL_F);     // ref's NEG_FILL
    }

    // label histogram, single block (no cross-block ordering needed)
    __shared__ int lh[512];
    if (blockIdx.x == 0) {
        for (int i = tid; i < 512; i += 256) lh[i] = 0;
        __syncthreads();
        for (int i = tid; i < BN; i += 256) atomicAdd(&lh[labels[i]], 1);
        __syncthreads();
        for (int i = tid; i < 512; i += 256) hist[i] = lh[i];
    }
}

// ---------------- main: split-bf16 MFMA Gram + fused distance/masked min-max ------
// One block per upper-tri 128x128 tile pair. 4 waves, each owns a 64x64 sub-tile.
// Double-buffered LDS staging (m97 structure): loads for kb+1 issued after the
// barrier, in flight during compute of kb.
__global__ __launch_bounds__(256) void tl_main(const ushort* __restrict__ Ehi,
                                               const ushort* __restrict__ Elo,
                                               const int* __restrict__ labels,
                                               const float* __restrict__ norms,
                                               unsigned* __restrict__ hp,
                                               unsigned* __restrict__ hn) {
    // Per buffer: [part: Ahi,Alo,Bhi,Blo][kc 0..3][m 0..127][8 bf16] = 32 KB
    __shared__ __align__(16) ushort smem[2][16384];

    const int tid  = threadIdx.x;
    const int lane = tid & 63;
    const int wave = tid >> 6;
    const int wy = wave >> 1, wx = wave & 1;
    const int quad = lane >> 4, l15 = lane & 15;

    // decode blockIdx -> (ib <= jb) upper-tri pair (scalar loop, ~32 SALU iters)
    int t = blockIdx.x, ib = 0, off = 0;
    while (off + (NBLK - ib) <= t) { off += NBLK - ib; ++ib; }
    const int jb = ib + (t - off);
    const int i0 = ib * 128, j0 = jb * 128;

    f32x4 acc[4][4];
    #pragma unroll
    for (int r = 0; r < 4; ++r)
        #pragma unroll
        for (int c = 0; c < 4; ++c)
            acc[r][c] = (f32x4){0.f, 0.f, 0.f, 0.f};

    // stage one 32-k slab (A hi/lo + B hi/lo) into buffer `buf`
    auto stage = [&](int kb, int buf) {
        #pragma unroll
        for (int s = 0; s < 8; ++s) {
            const int idx  = s * 256 + tid;          // 2048 16B chunks
            const int part = idx >> 9;               // 0:Ahi 1:Alo 2:Bhi 3:Blo
            const int kc   = (idx >> 7) & 3;
            const int m    = idx & 127;
            const ushort* src = (part & 1) ? Elo : Ehi;
            const int     base = (part < 2) ? i0 : j0;
            src += ((size_t)((kb * 4 + kc) * BN + base + m)) << 3;
            gld_lds16(src, &smem[buf][idx << 3]);
        }
    };

    stage(0, 0);                       // prologue
    for (int kb = 0; kb < DIM / 32; ++kb) {
        const int buf = kb & 1;
        // drains vmcnt for stage(kb) AND guarantees all waves done reading
        // smem[buf^1] (kb-1's compute) before stage(kb+1) overwrites it.
        __syncthreads();
        if (kb + 1 < DIM / 32) stage(kb + 1, buf ^ 1);

        const ushort* sb = &smem[buf][0];
        bf16x8 ah[4], al[4];
        #pragma unroll
        for (int r = 0; r < 4; ++r) {
            const int mi = wy * 64 + r * 16 + l15;
            ah[r] = *reinterpret_cast<const bf16x8*>(&sb[(0 * 512 + quad * 128 + mi) * 8]);
            al[r] = *reinterpret_cast<const bf16x8*>(&sb[(1 * 512 + quad * 128 + mi) * 8]);
        }
        #pragma unroll
        for (int c = 0; c < 4; ++c) {
            const int ni = wx * 64 + c * 16 + l15;
            bf16x8 bh = *reinterpret_cast<const bf16x8*>(&sb[(2 * 512 + quad * 128 + ni) * 8]);
            bf16x8 bl = *reinterpret_cast<const bf16x8*>(&sb[(3 * 512 + quad * 128 + ni) * 8]);
            #pragma unroll
            for (int r = 0; r < 4; ++r) {
                acc[r][c] = __builtin_amdgcn_mfma_f32_16x16x32_bf16(ah[r], bh, acc[r][c], 0, 0, 0);
                acc[r][c] = __builtin_amdgcn_mfma_f32_16x16x32_bf16(ah[r], bl, acc[r][c], 0, 0, 0);
                acc[r][c] = __builtin_amdgcn_mfma_f32_16x16x32_bf16(al[r], bh, acc[r][c], 0, 0, 0);
            }
        }
    }

    // ---------- epilogue: dots -> distances -> masked row & col stats ----------
    // C layout (16x16x32): col = lane&15, row = quad*4 + reg   [measured m89/m91]
    const int rowBase = i0 + wy * 64;
    const int colBase = j0 + wx * 64;

    float nrow[4][4]; int lrow[4][4];
    #pragma unroll
    for (int r = 0; r < 4; ++r)
        #pragma unroll
        for (int e = 0; e < 4; ++e) {
            const int g = rowBase + r * 16 + quad * 4 + e;
            nrow[r][e] = norms[g];
            lrow[r][e] = labels[g];
        }
    float ncol[4]; int lcol[4];
    #pragma unroll
    for (int c = 0; c < 4; ++c) {
        const int g = colBase + c * 16 + l15;
        ncol[c] = norms[g];
        lcol[c] = labels[g];
    }

    float rmax[4][4], rmin[4][4], cmax[4], cmin[4];
    #pragma unroll
    for (int r = 0; r < 4; ++r)
        #pragma unroll
        for (int e = 0; e < 4; ++e) { rmax[r][e] = 0.0f; rmin[r][e] = NEG_FILL_F; }
    #pragma unroll
    for (int c = 0; c < 4; ++c) { cmax[c] = 0.0f; cmin[c] = NEG_FILL_F; }

    #pragma unroll
    for (int c = 0; c < 4; ++c) {
        const int gcol = colBase + c * 16 + l15;
        #pragma unroll
        for (int r = 0; r < 4; ++r) {
            #pragma unroll
            for (int e = 0; e < 4; ++e) {
                const int grow = rowBase + r * 16 + quad * 4 + e;
                float d2 = nrow[r][e] + ncol[c] - 2.0f * acc[r][c][e];
                d2 = fmaxf(d2, 0.0f);
                const float d = (d2 > 0.0f) ? sqrtf(d2) : 0.0f;
                if (lrow[r][e] == lcol[c]) {
                    if (grow != gcol) {
                        rmax[r][e] = fmaxf(rmax[r][e], d);
                        cmax[c]    = fmaxf(cmax[c], d);
                    }
                } else {
                    rmin[r][e] = fminf(rmin[r][e], d);
                    cmin[c]    = fminf(cmin[c], d);
                }
            }
        }
    }

    // row stats: reduce across the 16 lanes of each quad (lane bits 0..3)
    #pragma unroll
    for (int m = 1; m <= 8; m <<= 1) {
        #pragma unroll
        for (int r = 0; r < 4; ++r)
            #pragma unroll
            for (int e = 0; e < 4; ++e) {
                rmax[r][e] = fmaxf(rmax[r][e], __shfl_xor(rmax[r][e], m, 64));
                rmin[r][e] = fminf(rmin[r][e], __shfl_xor(rmin[r][e], m, 64));
            }
    }
    // col stats: reduce across quads (lane bits 4..5)
    #pragma unroll
    for (int m = 16; m <= 32; m <<= 1) {
        #pragma unroll
        for (int c = 0; c < 4; ++c) {
            cmax[c] = fmaxf(cmax[c], __shfl_xor(cmax[c], m, 64));
            cmin[c] = fminf(cmin[c], __shfl_xor(cmin[c], m, 64));
        }
    }

    // block-level combine in LDS (reuse staging memory), then global atomics
    unsigned* srhp = reinterpret_cast<unsigned*>(&smem[0][0]);  // [128]
    unsigned* srhn = srhp + 128;
    unsigned* schp = srhp + 256;
    unsigned* schn = srhp + 384;
    __syncthreads();   // all frag reads done; safe to overwrite smem
    if (tid < 128) {
        srhp[tid] = 0u;
        srhn[tid] = __float_as_uint(NEG_FILL_F);
        schp[tid] = 0u;
        schn[tid] = __float_as_uint(NEG_FILL_F);
    }
    __syncthreads();
    if (l15 == 0) {   // lanes 0,16,32,48 hold row results for their quad
        #pragma unroll
        for (int r = 0; r < 4; ++r)
            #pragma unroll
            for (int e = 0; e < 4; ++e) {
                const int lr = wy * 64 + r * 16 + quad * 4 + e;
                atomicMax(&srhp[lr], __float_as_uint(rmax[r][e]));
                atomicMin(&srhn[lr], __float_as_uint(rmin[r][e]));
            }
    }
    if (quad == 0) {  // lanes 0..15 hold col results
        #pragma unroll
        for (int c = 0; c < 4; ++c) {
            const int lc = wx * 64 + c * 16 + l15;
            atomicMax(&schp[lc], __float_as_uint(cmax[c]));
            atomicMin(&schn[lc], __float_as_uint(cmin[c]));
        }
    }
    __syncthreads();
    if (tid < 128) {
        atomicMax(&hp[i0 + tid], srhp[tid]);   // uint order == float order for x>=0
        atomicMin(&hn[i0 + tid], srhn[tid]);
        atomicMax(&hp[j0 + tid], schp[tid]);   // transposed contribution (d symmetric)
        atomicMin(&hn[j0 + tid], schn[tid]);
    }
}

// ---------------- final scalar reduction ----------------
__global__ __launch_bounds__(1024) void tl_finish(const unsigned* __restrict__ hp,
                                                  const unsigned* __restrict__ hn,
                                                  const int* __restrict__ labels,
                                                  const int* __restrict__ hist,
                                                  float* __restrict__ out) {
    __shared__ float ssum[16];
    __shared__ float scnt[16];
    const int t = threadIdx.x;
    float sum = 0.0f, cnt = 0.0f;
    for (int i = t; i < BN; i += 1024) {
        const int h = hist[labels[i]];
        const bool valid = (h >= 2) && (h < BN);   // has_pos && has_neg
        const float per = fmaxf(__uint_as_float(hp[i]) - __uint_as_float(hn[i]) + MARGIN_F, 0.0f);
        if (valid) { sum += per; cnt += 1.0f; }
    }
    #pragma unroll
    for (int m = 32; m; m >>= 1) {
        sum += __shfl_xor(sum, m, 64);
        cnt += __shfl_xor(cnt, m, 64);
    }
    const int wid = t >> 6;
    if ((t & 63) == 0) { ssum[wid] = sum; scnt[wid] = cnt; }
    __syncthreads();
    if (t == 0) {
        float S = 0.0f, C = 0.0f;
        #pragma unroll
        for (int w = 0; w < 16; ++w) { S += ssum[w]; C += scnt[w]; }
        out[0] = (C > 0.0f) ? (S / fmaxf(C, 1.0f)) : 0.0f;
    }
}

extern "C" void kernel_launch(void* const* d_in, const int* in_sizes, int n_in,
                              void* d_out, int out_size, void* d_ws, size_t ws_size,
                              hipStream_t stream) {
    const float* E      = (const float*)d_in[0];
    const int*   labels = (const int*)d_in[1];

    float*    ws    = (float*)d_ws;
    float*    norms = ws;                          // [4096] f32
    unsigned* hp    = (unsigned*)(ws + 4096);      // [4096] u32
    unsigned* hn    = (unsigned*)(ws + 8192);      // [4096] u32
    int*      hist  = (int*)(ws + 12288);          // [512]  i32
    ushort*   Ehi   = (ushort*)(ws + 16384);       // [32][4096][8] bf16 = 2 MB
    ushort*   Elo   = Ehi + (size_t)BN * DIM;      // 2 MB

    tl_prep<<<BN / 4, 256, 0, stream>>>(E, labels, norms, hp, hn, hist, Ehi, Elo);
    tl_main<<<NPAIR, 256, 0, stream>>>(Ehi, Elo, labels, norms, hp, hn);
    tl_finish<<<1, 1024, 0, stream>>>(hp, hn, labels, hist, (float*)d_out);
}